// Round 3
// baseline (520.454 us; speedup 1.0000x reference)
//
#include <hip/hip_runtime.h>
#include <math.h>

#define BN_EPS 1e-5f

constexpr int B  = 4;
constexpr int C  = 256;
constexpr int HW = 4096;   // 64*64
constexpr int CK = 64;
constexpr int CV = 256;
constexpr int COB = 40;    // output channels per kv block (8 blocks cover 320)
constexpr int CHG = 2;     // channel groups in attn (128 ch each)

typedef short bf16x8 __attribute__((ext_vector_type(8)));
typedef float f32x4  __attribute__((ext_vector_type(4)));

__device__ __forceinline__ ushort f2bf(float f) {
    unsigned u = __float_as_uint(f);
    u += 0x7FFFu + ((u >> 16) & 1u);      // round to nearest even
    return (ushort)(u >> 16);
}
__device__ __forceinline__ float bf2f(ushort u) {
    return __uint_as_float((unsigned)u << 16);
}

// ---------------------------------------------------------------------------
// Kernel 1: K = BN(Wk x + bk) -> bf16 [b][hw][ck]   (ck contiguous)
//           V = Wv x + bv     -> bf16 [b][cv][hw]   (hw contiguous)
// COB=40 -> 512 blocks -> 2 blocks/CU for latency hiding.
// ---------------------------------------------------------------------------
__global__ __launch_bounds__(256) void kv_kernel(
    const float* __restrict__ x,  const float* __restrict__ Wk, const float* __restrict__ bk,
    const float* __restrict__ gamma, const float* __restrict__ beta,
    const float* __restrict__ mean,  const float* __restrict__ var,
    const float* __restrict__ Wv, const float* __restrict__ bv,
    ushort* __restrict__ Kbuf, ushort* __restrict__ Vbuf)
{
    __shared__ float xs[32][256];     // 32 KB
    __shared__ float wls[32][COB];    // 5 KB

    const int t   = threadIdx.x;
    const int hw0 = blockIdx.x * 256;
    const int co0 = blockIdx.y * COB;
    const int b   = blockIdx.z;

    float acc[COB];
#pragma unroll
    for (int i = 0; i < COB; i++) acc[i] = 0.f;

    const float* xb = x + (size_t)b * C * HW;

    for (int c0 = 0; c0 < C; c0 += 32) {
#pragma unroll
        for (int r = 0; r < 8; r++) {
            int qq = r * 256 + t;
            int c  = qq >> 6;
            int h4 = (qq & 63) * 4;
            *(float4*)&xs[c][h4] = *(const float4*)&xb[(size_t)(c0 + c) * HW + hw0 + h4];
        }
#pragma unroll
        for (int r = 0; r < 5; r++) {             // 1280 = 5*256 weights
            int idx = r * 256 + t;
            int ci  = idx / COB;
            int coi = idx % COB;
            int co  = co0 + coi;
            wls[ci][coi] = (co < CK) ? Wk[co * C + c0 + ci]
                                     : Wv[(co - CK) * C + c0 + ci];
        }
        __syncthreads();

#pragma unroll
        for (int ci = 0; ci < 32; ci++) {
            float xv = xs[ci][t];
#pragma unroll
            for (int qq = 0; qq < COB / 4; qq++) {
                float4 w4 = *(const float4*)&wls[ci][qq * 4];
                acc[qq * 4 + 0] += w4.x * xv;
                acc[qq * 4 + 1] += w4.y * xv;
                acc[qq * 4 + 2] += w4.z * xv;
                acc[qq * 4 + 3] += w4.w * xv;
            }
        }
        __syncthreads();
    }

    const int hw = hw0 + t;
    ushort* Krow = Kbuf + ((size_t)b * HW + hw) * CK;
#pragma unroll
    for (int coi = 0; coi < COB; coi++) {
        int co = co0 + coi;
        float v = acc[coi];
        if (co < CK) {
            float inv = gamma[co] * rsqrtf(var[co] + BN_EPS);
            v = (v + bk[co]) * inv + (beta[co] - mean[co] * inv);
            Krow[co] = f2bf(v);
        } else {
            int cv = co - CK;
            Vbuf[((size_t)b * CV + cv) * HW + hw] = f2bf(v + bv[cv]);
        }
    }
}

// ---------------------------------------------------------------------------
// Kernel 1.5: per-row K norms + per-batch max norm.
// bound_i = ||K_i|| * max_j ||K_j||  >= rowmax(energy)  (Cauchy-Schwarz),
// used instead of online softmax max tracking.
// ---------------------------------------------------------------------------
__global__ __launch_bounds__(256) void norm_kernel(
    const ushort* __restrict__ Kbuf, float* __restrict__ mb, unsigned* __restrict__ Mx)
{
    __shared__ float red[4];
    const int t   = threadIdx.x;
    const int b   = blockIdx.y;
    const int row = blockIdx.x * 256 + t;

    const ushort* kp = Kbuf + ((size_t)b * HW + row) * CK;
    float ss = 0.f;
#pragma unroll
    for (int k = 0; k < 8; k++) {
        bf16x8 v = *(const bf16x8*)(kp + k * 8);
#pragma unroll
        for (int e = 0; e < 8; e++) {
            float f = bf2f((ushort)v[e]);
            ss += f * f;
        }
    }
    float nr = sqrtf(ss);
    mb[(size_t)b * HW + row] = nr;

    float mx = nr;
#pragma unroll
    for (int off = 1; off <= 32; off <<= 1)
        mx = fmaxf(mx, __shfl_xor(mx, off, 64));
    if ((t & 63) == 0) red[t >> 6] = mx;
    __syncthreads();
    if (t == 0) {
        float m = fmaxf(fmaxf(red[0], red[1]), fmaxf(red[2], red[3]));
        atomicMax(Mx + b, __float_as_uint(m));   // positive floats: uint order == float order
    }
}

// ---------------------------------------------------------------------------
// Kernel 2: MFMA flash attention, bound-softmax (no running max / rescale).
// Grid (64 i-tiles, CHG ch groups, B). 4 waves.
// Wave wv: S rows wv*16..+15; PV channels chg*128 + wv*32 .. +32.
// kf double-buffered (next tile prefetch); P via LDS bf16 round-trip.
// ---------------------------------------------------------------------------
__global__ __launch_bounds__(256, 2) void attn_kernel(
    const ushort* __restrict__ Kbuf, const ushort* __restrict__ Vbuf,
    const float* __restrict__ mb, const unsigned* __restrict__ Mx,
    float* __restrict__ out)
{
    __shared__ __align__(16) ushort Ps[64][72];   // [i][j] bf16, pad 72
    __shared__ float l_s[64];

    const int t    = threadIdx.x;
    const int lane = t & 63;
    const int wv   = t >> 6;          // 0..3
    const int q    = lane >> 4;       // quad 0..3
    const int col  = lane & 15;
    const int b    = blockIdx.z;
    const int chg  = blockIdx.y;
    const int i0g  = blockIdx.x * 64;

    const ushort* Kb = Kbuf + (size_t)b * HW * CK;
    const ushort* Vb = Vbuf + (size_t)b * CV * HW;

    // Q A-frags: A[m=i][k=ck]
    bf16x8 qa[2];
#pragma unroll
    for (int k = 0; k < 2; k++)
        qa[k] = *(const bf16x8*)(Kb + (size_t)(i0g + wv * 16 + col) * CK + k * 32 + q * 8);

    // per-row exp bound
    const float Mxf = __uint_as_float(Mx[b]);
    float m_i[4];
#pragma unroll
    for (int r = 0; r < 4; r++)
        m_i[r] = mb[(size_t)b * HW + i0g + wv * 16 + q * 4 + r] * Mxf;

    f32x4 Oacc[2][4];
#pragma unroll
    for (int mt = 0; mt < 2; mt++)
#pragma unroll
        for (int nt = 0; nt < 4; nt++)
            Oacc[mt][nt] = (f32x4){0.f, 0.f, 0.f, 0.f};

    float l_r[4] = {0.f, 0.f, 0.f, 0.f};
    const f32x4 zf = (f32x4){0.f, 0.f, 0.f, 0.f};
    const int cbase = chg * 128 + wv * 32;

    // preload K tile 0
    bf16x8 kf[2][4][2];
#pragma unroll
    for (int nt = 0; nt < 4; nt++)
#pragma unroll
        for (int k = 0; k < 2; k++)
            kf[0][nt][k] = *(const bf16x8*)(Kb + (size_t)(nt * 16 + col) * CK + k * 32 + q * 8);

    for (int j0 = 0; j0 < HW; j0 += 64) {
        const int pc = (j0 >> 6) & 1, pn = pc ^ 1;
        const int jn = (j0 + 64) & (HW - 1);

        // prefetch next K tile (consumed next iteration)
#pragma unroll
        for (int nt = 0; nt < 4; nt++)
#pragma unroll
            for (int k = 0; k < 2; k++)
                kf[pn][nt][k] = *(const bf16x8*)(Kb + (size_t)(jn + nt * 16 + col) * CK + k * 32 + q * 8);

        // current V tile: A[m=c][k=j]  (consumed after 2 barriers)
        bf16x8 vf[2][2];
#pragma unroll
        for (int mt = 0; mt < 2; mt++)
#pragma unroll
            for (int k = 0; k < 2; k++)
                vf[mt][k] = *(const bf16x8*)(Vb + (size_t)(cbase + mt * 16 + col) * HW + j0 + k * 32 + q * 8);

        // S = Q.K : 8 MFMA
        f32x4 S[4];
#pragma unroll
        for (int nt = 0; nt < 4; nt++) {
            S[nt] = __builtin_amdgcn_mfma_f32_16x16x32_bf16(qa[0], kf[pc][nt][0], zf, 0, 0, 0);
            S[nt] = __builtin_amdgcn_mfma_f32_16x16x32_bf16(qa[1], kf[pc][nt][1], S[nt], 0, 0, 0);
        }

        // p = exp(S - bound); l accumulates per-lane (no shuffles in loop)
        float p[4][4];
#pragma unroll
        for (int nt = 0; nt < 4; nt++)
#pragma unroll
            for (int r = 0; r < 4; r++)
                p[nt][r] = __expf(S[nt][r] - m_i[r]);
#pragma unroll
        for (int r = 0; r < 4; r++)
            l_r[r] += (p[0][r] + p[1][r]) + (p[2][r] + p[3][r]);

        __syncthreads();   // prior PV reads of Ps complete
#pragma unroll
        for (int nt = 0; nt < 4; nt++)
#pragma unroll
            for (int r = 0; r < 4; r++)
                Ps[wv * 16 + q * 4 + r][nt * 16 + col] = f2bf(p[nt][r]);
        __syncthreads();   // Ps visible

        // PV: D[c][i] += V.P
        bf16x8 pf[4][2];
#pragma unroll
        for (int nt = 0; nt < 4; nt++)
#pragma unroll
            for (int k = 0; k < 2; k++)
                pf[nt][k] = *(const bf16x8*)&Ps[nt * 16 + col][k * 32 + q * 8];
#pragma unroll
        for (int mt = 0; mt < 2; mt++)
#pragma unroll
            for (int nt = 0; nt < 4; nt++) {
                Oacc[mt][nt] = __builtin_amdgcn_mfma_f32_16x16x32_bf16(vf[mt][0], pf[nt][0], Oacc[mt][nt], 0, 0, 0);
                Oacc[mt][nt] = __builtin_amdgcn_mfma_f32_16x16x32_bf16(vf[mt][1], pf[nt][1], Oacc[mt][nt], 0, 0, 0);
            }
    }

    // final l reduction across the 16 col-lanes of each row
#pragma unroll
    for (int r = 0; r < 4; r++) {
        float v = l_r[r];
#pragma unroll
        for (int off = 1; off <= 8; off <<= 1)
            v += __shfl_xor(v, off, 64);
        if (col == 0) l_s[wv * 16 + q * 4 + r] = v;
    }
    __syncthreads();

    float linv[4];
#pragma unroll
    for (int nt = 0; nt < 4; nt++) linv[nt] = 1.0f / l_s[nt * 16 + col];

    float* ob = out + (size_t)b * CV * HW;
#pragma unroll
    for (int mt = 0; mt < 2; mt++)
#pragma unroll
        for (int r = 0; r < 4; r++) {
            size_t c = cbase + mt * 16 + q * 4 + r;
#pragma unroll
            for (int nt = 0; nt < 4; nt++)
                ob[c * HW + i0g + nt * 16 + col] = Oacc[mt][nt][r] * linv[nt];
        }
}

// ---------------------------------------------------------------------------
extern "C" void kernel_launch(void* const* d_in, const int* in_sizes, int n_in,
                              void* d_out, int out_size, void* d_ws, size_t ws_size,
                              hipStream_t stream)
{
    const float* x     = (const float*)d_in[0];
    const float* Wk    = (const float*)d_in[1];
    const float* bk    = (const float*)d_in[2];
    const float* gamma = (const float*)d_in[3];
    const float* beta  = (const float*)d_in[4];
    const float* mean  = (const float*)d_in[5];
    const float* var   = (const float*)d_in[6];
    const float* Wv    = (const float*)d_in[7];
    const float* bv    = (const float*)d_in[8];
    float* out = (float*)d_out;

    ushort*   Kbuf = (ushort*)d_ws;                         // [B][HW][CK] bf16, 2 MB
    ushort*   Vbuf = Kbuf + (size_t)B * HW * CK;            // [B][CV][HW] bf16, 8.4 MB
    float*    mb   = (float*)(Vbuf + (size_t)B * CV * HW);  // [B][HW] fp32, 64 KB
    unsigned* Mx   = (unsigned*)(mb + (size_t)B * HW);      // [B]

    hipMemsetAsync(Mx, 0, B * sizeof(unsigned), stream);

    dim3 g1(HW / 256, 320 / COB, B);                        // (16,8,4)
    kv_kernel<<<g1, 256, 0, stream>>>(x, Wk, bk, gamma, beta, mean, var, Wv, bv,
                                      Kbuf, Vbuf);

    dim3 gn(HW / 256, B);                                   // (16,4)
    norm_kernel<<<gn, 256, 0, stream>>>(Kbuf, mb, Mx);

    dim3 g2(HW / 64, CHG, B);                               // (64,2,4)
    attn_kernel<<<g2, 256, 0, stream>>>(Kbuf, Vbuf, mb, Mx, out);
}

// Round 4
// 317.140 us; speedup vs baseline: 1.6411x; 1.6411x over previous
//
#include <hip/hip_runtime.h>
#include <math.h>

#define BN_EPS 1e-5f

constexpr int B  = 4;
constexpr int C  = 256;
constexpr int HW = 4096;   // 64*64
constexpr int CK = 64;
constexpr int CV = 256;
constexpr int COB = 40;    // output channels per kv block (8 blocks cover 320)
constexpr int CHG = 2;     // channel groups in attn (128 ch each)

typedef short bf16x8 __attribute__((ext_vector_type(8)));
typedef float f32x4  __attribute__((ext_vector_type(4)));

__device__ __forceinline__ ushort f2bf(float f) {
    unsigned u = __float_as_uint(f);
    u += 0x7FFFu + ((u >> 16) & 1u);      // round to nearest even
    return (ushort)(u >> 16);
}
__device__ __forceinline__ float bf2f(ushort u) {
    return __uint_as_float((unsigned)u << 16);
}

// ---------------------------------------------------------------------------
// Kernel 1: K = BN(Wk x + bk) -> bf16 [b][hw][ck]   (ck contiguous)
//           V = Wv x + bv     -> bf16 [b][cv][hw]   (hw contiguous)
// ---------------------------------------------------------------------------
__global__ __launch_bounds__(256) void kv_kernel(
    const float* __restrict__ x,  const float* __restrict__ Wk, const float* __restrict__ bk,
    const float* __restrict__ gamma, const float* __restrict__ beta,
    const float* __restrict__ mean,  const float* __restrict__ var,
    const float* __restrict__ Wv, const float* __restrict__ bv,
    ushort* __restrict__ Kbuf, ushort* __restrict__ Vbuf)
{
    __shared__ float xs[32][256];     // 32 KB
    __shared__ float wls[32][COB];    // 5 KB

    const int t   = threadIdx.x;
    const int hw0 = blockIdx.x * 256;
    const int co0 = blockIdx.y * COB;
    const int b   = blockIdx.z;

    float acc[COB];
#pragma unroll
    for (int i = 0; i < COB; i++) acc[i] = 0.f;

    const float* xb = x + (size_t)b * C * HW;

    for (int c0 = 0; c0 < C; c0 += 32) {
#pragma unroll
        for (int r = 0; r < 8; r++) {
            int qq = r * 256 + t;
            int c  = qq >> 6;
            int h4 = (qq & 63) * 4;
            *(float4*)&xs[c][h4] = *(const float4*)&xb[(size_t)(c0 + c) * HW + hw0 + h4];
        }
#pragma unroll
        for (int r = 0; r < 5; r++) {             // 1280 = 5*256 weights
            int idx = r * 256 + t;
            int ci  = idx / COB;
            int coi = idx % COB;
            int co  = co0 + coi;
            wls[ci][coi] = (co < CK) ? Wk[co * C + c0 + ci]
                                     : Wv[(co - CK) * C + c0 + ci];
        }
        __syncthreads();

#pragma unroll
        for (int ci = 0; ci < 32; ci++) {
            float xv = xs[ci][t];
#pragma unroll
            for (int qq = 0; qq < COB / 4; qq++) {
                float4 w4 = *(const float4*)&wls[ci][qq * 4];
                acc[qq * 4 + 0] += w4.x * xv;
                acc[qq * 4 + 1] += w4.y * xv;
                acc[qq * 4 + 2] += w4.z * xv;
                acc[qq * 4 + 3] += w4.w * xv;
            }
        }
        __syncthreads();
    }

    const int hw = hw0 + t;
    ushort* Krow = Kbuf + ((size_t)b * HW + hw) * CK;
#pragma unroll
    for (int coi = 0; coi < COB; coi++) {
        int co = co0 + coi;
        float v = acc[coi];
        if (co < CK) {
            float inv = gamma[co] * rsqrtf(var[co] + BN_EPS);
            v = (v + bk[co]) * inv + (beta[co] - mean[co] * inv);
            Krow[co] = f2bf(v);
        } else {
            int cv = co - CK;
            Vbuf[((size_t)b * CV + cv) * HW + hw] = f2bf(v + bv[cv]);
        }
    }
}

// ---------------------------------------------------------------------------
// Kernel 1.5: per-row K norms + per-batch max norm (Cauchy-Schwarz bound
// replaces online-softmax running max).
// ---------------------------------------------------------------------------
__global__ __launch_bounds__(256) void norm_kernel(
    const ushort* __restrict__ Kbuf, float* __restrict__ mb, unsigned* __restrict__ Mx)
{
    __shared__ float red[4];
    const int t   = threadIdx.x;
    const int b   = blockIdx.y;
    const int row = blockIdx.x * 256 + t;

    const ushort* kp = Kbuf + ((size_t)b * HW + row) * CK;
    float ss = 0.f;
#pragma unroll
    for (int k = 0; k < 8; k++) {
        bf16x8 v = *(const bf16x8*)(kp + k * 8);
#pragma unroll
        for (int e = 0; e < 8; e++) {
            float f = bf2f((ushort)v[e]);
            ss += f * f;
        }
    }
    float nr = sqrtf(ss);
    mb[(size_t)b * HW + row] = nr;

    float mx = nr;
#pragma unroll
    for (int off = 1; off <= 32; off <<= 1)
        mx = fmaxf(mx, __shfl_xor(mx, off, 64));
    if ((t & 63) == 0) red[t >> 6] = mx;
    __syncthreads();
    if (t == 0) {
        float m = fmaxf(fmaxf(red[0], red[1]), fmaxf(red[2], red[3]));
        atomicMax(Mx + b, __float_as_uint(m));
    }
}

// ---------------------------------------------------------------------------
// Kernel 2: MFMA flash attention, bound-softmax, STATIC double-buffered K
// prefetch (j-loop unrolled 2x so all local-array indices are compile-time —
// R3's runtime-indexed kf[] spilled to scratch: 1 GB of WRITE_SIZE).
// ---------------------------------------------------------------------------
#define ATTN_TILE(KC, KN, J0, JN)                                              \
    {                                                                          \
        const int j0_ = (J0), jn_ = (JN);                                      \
        _Pragma("unroll")                                                      \
        for (int nt = 0; nt < 4; nt++)                                         \
            _Pragma("unroll")                                                  \
            for (int k = 0; k < 2; k++)                                        \
                KN[nt][k] = *(const bf16x8*)(Kb + (size_t)(jn_ + nt * 16 + col) * CK + k * 32 + q * 8); \
        bf16x8 vf[2][2];                                                       \
        _Pragma("unroll")                                                      \
        for (int mt = 0; mt < 2; mt++)                                         \
            _Pragma("unroll")                                                  \
            for (int k = 0; k < 2; k++)                                        \
                vf[mt][k] = *(const bf16x8*)(Vb + (size_t)(cbase + mt * 16 + col) * HW + j0_ + k * 32 + q * 8); \
        f32x4 S[4];                                                            \
        _Pragma("unroll")                                                      \
        for (int nt = 0; nt < 4; nt++) {                                       \
            S[nt] = __builtin_amdgcn_mfma_f32_16x16x32_bf16(qa[0], KC[nt][0], zf, 0, 0, 0); \
            S[nt] = __builtin_amdgcn_mfma_f32_16x16x32_bf16(qa[1], KC[nt][1], S[nt], 0, 0, 0); \
        }                                                                      \
        float p[4][4];                                                         \
        _Pragma("unroll")                                                      \
        for (int nt = 0; nt < 4; nt++)                                         \
            _Pragma("unroll")                                                  \
            for (int r = 0; r < 4; r++)                                        \
                p[nt][r] = __expf(S[nt][r] - m_i[r]);                          \
        _Pragma("unroll")                                                      \
        for (int r = 0; r < 4; r++)                                            \
            l_r[r] += (p[0][r] + p[1][r]) + (p[2][r] + p[3][r]);               \
        __syncthreads();                                                       \
        _Pragma("unroll")                                                      \
        for (int nt = 0; nt < 4; nt++)                                         \
            _Pragma("unroll")                                                  \
            for (int r = 0; r < 4; r++)                                        \
                Ps[wv * 16 + q * 4 + r][nt * 16 + col] = f2bf(p[nt][r]);       \
        __syncthreads();                                                       \
        bf16x8 pf[4][2];                                                       \
        _Pragma("unroll")                                                      \
        for (int nt = 0; nt < 4; nt++)                                         \
            _Pragma("unroll")                                                  \
            for (int k = 0; k < 2; k++)                                        \
                pf[nt][k] = *(const bf16x8*)&Ps[nt * 16 + col][k * 32 + q * 8]; \
        _Pragma("unroll")                                                      \
        for (int mt = 0; mt < 2; mt++)                                         \
            _Pragma("unroll")                                                  \
            for (int nt = 0; nt < 4; nt++) {                                   \
                Oacc[mt][nt] = __builtin_amdgcn_mfma_f32_16x16x32_bf16(vf[mt][0], pf[nt][0], Oacc[mt][nt], 0, 0, 0); \
                Oacc[mt][nt] = __builtin_amdgcn_mfma_f32_16x16x32_bf16(vf[mt][1], pf[nt][1], Oacc[mt][nt], 0, 0, 0); \
            }                                                                  \
    }

__global__ __launch_bounds__(256, 2) void attn_kernel(
    const ushort* __restrict__ Kbuf, const ushort* __restrict__ Vbuf,
    const float* __restrict__ mb, const unsigned* __restrict__ Mx,
    float* __restrict__ out)
{
    __shared__ __align__(16) ushort Ps[64][72];   // [i][j] bf16, pad 72
    __shared__ float l_s[64];

    const int t    = threadIdx.x;
    const int lane = t & 63;
    const int wv   = t >> 6;          // 0..3
    const int q    = lane >> 4;       // quad 0..3
    const int col  = lane & 15;
    const int b    = blockIdx.z;
    const int chg  = blockIdx.y;
    const int i0g  = blockIdx.x * 64;

    const ushort* Kb = Kbuf + (size_t)b * HW * CK;
    const ushort* Vb = Vbuf + (size_t)b * CV * HW;

    // Q A-frags: A[m=i][k=ck]
    bf16x8 qa[2];
#pragma unroll
    for (int k = 0; k < 2; k++)
        qa[k] = *(const bf16x8*)(Kb + (size_t)(i0g + wv * 16 + col) * CK + k * 32 + q * 8);

    // per-row exp bound
    const float Mxf = __uint_as_float(Mx[b]);
    float m_i[4];
#pragma unroll
    for (int r = 0; r < 4; r++)
        m_i[r] = mb[(size_t)b * HW + i0g + wv * 16 + q * 4 + r] * Mxf;

    f32x4 Oacc[2][4];
#pragma unroll
    for (int mt = 0; mt < 2; mt++)
#pragma unroll
        for (int nt = 0; nt < 4; nt++)
            Oacc[mt][nt] = (f32x4){0.f, 0.f, 0.f, 0.f};

    float l_r[4] = {0.f, 0.f, 0.f, 0.f};
    const f32x4 zf = (f32x4){0.f, 0.f, 0.f, 0.f};
    const int cbase = chg * 128 + wv * 32;

    // preload K tile 0 into kf0 (static buffers; indices all compile-time)
    bf16x8 kf0[4][2], kf1[4][2];
#pragma unroll
    for (int nt = 0; nt < 4; nt++)
#pragma unroll
        for (int k = 0; k < 2; k++)
            kf0[nt][k] = *(const bf16x8*)(Kb + (size_t)(nt * 16 + col) * CK + k * 32 + q * 8);

    for (int j0 = 0; j0 < HW; j0 += 128) {
        ATTN_TILE(kf0, kf1, j0,      j0 + 64);
        ATTN_TILE(kf1, kf0, j0 + 64, (j0 + 128) & (HW - 1));
    }

    // final l reduction across the 16 col-lanes of each row
#pragma unroll
    for (int r = 0; r < 4; r++) {
        float v = l_r[r];
#pragma unroll
        for (int off = 1; off <= 8; off <<= 1)
            v += __shfl_xor(v, off, 64);
        if (col == 0) l_s[wv * 16 + q * 4 + r] = v;
    }
    __syncthreads();

    float linv[4];
#pragma unroll
    for (int nt = 0; nt < 4; nt++) linv[nt] = 1.0f / l_s[nt * 16 + col];

    float* ob = out + (size_t)b * CV * HW;
#pragma unroll
    for (int mt = 0; mt < 2; mt++)
#pragma unroll
        for (int r = 0; r < 4; r++) {
            size_t c = cbase + mt * 16 + q * 4 + r;
#pragma unroll
            for (int nt = 0; nt < 4; nt++)
                ob[c * HW + i0g + nt * 16 + col] = Oacc[mt][nt][r] * linv[nt];
        }
}

// ---------------------------------------------------------------------------
extern "C" void kernel_launch(void* const* d_in, const int* in_sizes, int n_in,
                              void* d_out, int out_size, void* d_ws, size_t ws_size,
                              hipStream_t stream)
{
    const float* x     = (const float*)d_in[0];
    const float* Wk    = (const float*)d_in[1];
    const float* bk    = (const float*)d_in[2];
    const float* gamma = (const float*)d_in[3];
    const float* beta  = (const float*)d_in[4];
    const float* mean  = (const float*)d_in[5];
    const float* var   = (const float*)d_in[6];
    const float* Wv    = (const float*)d_in[7];
    const float* bv    = (const float*)d_in[8];
    float* out = (float*)d_out;

    ushort*   Kbuf = (ushort*)d_ws;                         // [B][HW][CK] bf16, 2 MB
    ushort*   Vbuf = Kbuf + (size_t)B * HW * CK;            // [B][CV][HW] bf16, 8.4 MB
    float*    mb   = (float*)(Vbuf + (size_t)B * CV * HW);  // [B][HW] fp32, 64 KB
    unsigned* Mx   = (unsigned*)(mb + (size_t)B * HW);      // [B]

    hipMemsetAsync(Mx, 0, B * sizeof(unsigned), stream);

    dim3 g1(HW / 256, 320 / COB, B);                        // (16,8,4)
    kv_kernel<<<g1, 256, 0, stream>>>(x, Wk, bk, gamma, beta, mean, var, Wv, bv,
                                      Kbuf, Vbuf);

    dim3 gn(HW / 256, B);                                   // (16,4)
    norm_kernel<<<gn, 256, 0, stream>>>(Kbuf, mb, Mx);

    dim3 g2(HW / 64, CHG, B);                               // (64,2,4)
    attn_kernel<<<g2, 256, 0, stream>>>(Kbuf, Vbuf, mb, Mx, out);
}